// Round 18
// baseline (142.223 us; speedup 1.0000x reference)
//
#include <hip/hip_runtime.h>
#include <hip/hip_bf16.h>
#include <stdint.h>

#define T_TOK 4096
#define DIM   1024
#define NE    16
#define NDFF  1024
#define CAPN  512

typedef unsigned int   u32;
typedef unsigned short u16;
typedef __attribute__((ext_vector_type(8))) short bf16x8;
typedef __attribute__((ext_vector_type(4))) float f32x4;

// ---------- helpers ----------
__device__ __forceinline__ void gll16(void* lds, const void* g) {
  union { const void* p; const __attribute__((address_space(1))) void* q; } gu;
  union { void* p; __attribute__((address_space(3))) void* q; } lu;
  gu.p = g; lu.p = lds;
  __builtin_amdgcn_global_load_lds(gu.q, lu.q, 16, 0, 0);
}

__device__ __forceinline__ u16 f2bf(float f) {
  u32 u = __float_as_uint(f);
  u32 r = (u + 0x7FFFu + ((u >> 16) & 1u)) >> 16;   // RNE
  return (u16)r;
}

// gelu tanh-approx with fast exp: tanh(z) = 1 - 2/(e^{2z}+1)  (inf-safe both ends)
__device__ __forceinline__ float gelu_tanh(float x) {
  float x3 = x * x * x;
  float z = 0.7978845608028654f * (x + 0.044715f * x3);
  float t = __expf(2.0f * z);
  float th = 1.0f - 2.0f / (t + 1.0f);
  return 0.5f * x * (1.0f + th);
}

// ---------- K1: router (f32 exact), 4 tokens per 256-thr block ----------
__global__ __launch_bounds__(256) void router_kernel(
    const float* __restrict__ h, const float* __restrict__ Wr,
    float* __restrict__ logits, u32* __restrict__ topmask, u32* __restrict__ keptmask)
{
  const int t = blockIdx.x * 4 + (threadIdx.x >> 6);
  const int lane = threadIdx.x & 63;
  float acc[NE];
#pragma unroll
  for (int e = 0; e < NE; ++e) acc[e] = 0.f;
  const float* hrow = h + (size_t)t * DIM;
#pragma unroll 4
  for (int i = 0; i < DIM / 64; ++i) {
    int d = lane + 64 * i;
    float hv = hrow[d];
    const float4* wr4 = (const float4*)(Wr + (size_t)d * NE);
#pragma unroll
    for (int q = 0; q < 4; ++q) {
      float4 w = wr4[q];
      acc[q*4+0] += hv * w.x; acc[q*4+1] += hv * w.y;
      acc[q*4+2] += hv * w.z; acc[q*4+3] += hv * w.w;
    }
  }
#pragma unroll
  for (int e = 0; e < NE; ++e) {
    float v = acc[e];
#pragma unroll
    for (int off = 32; off; off >>= 1) v += __shfl_xor(v, off);
    acc[e] = v;
  }
  int m1 = 0; float b1 = acc[0];
#pragma unroll
  for (int e = 1; e < NE; ++e) if (acc[e] > b1) { b1 = acc[e]; m1 = e; }
  int m2 = 0; float b2 = -3.4e38f;
#pragma unroll
  for (int e = 0; e < NE; ++e) if (e != m1 && acc[e] > b2) { b2 = acc[e]; m2 = e; }
  if (lane < NE) logits[(size_t)t * NE + lane] = acc[lane];
  if (lane == 0) { topmask[t] = (1u << m1) | (1u << m2); keptmask[t] = 0u; }
}

// ---------- K2: per-expert capacity selection (exact, tie=lower index) ----------
__global__ __launch_bounds__(1024) void capacity_kernel(
    const float* __restrict__ logits, const u32* __restrict__ topmask,
    u32* __restrict__ keptmask, int* __restrict__ expert_tokens)
{
  const int e = blockIdx.x;
  const int tid = threadIdx.x;
  const int lane = tid & 63, wv = tid >> 6;
  __shared__ u32 wred[16];
  __shared__ u32 wscan[16];
  __shared__ u32 bcast;

  u32 key[4];
#pragma unroll
  for (int j = 0; j < 4; ++j) {
    int t = tid * 4 + j;
    float lg = logits[(size_t)t * NE + e];
    u32 u = __float_as_uint(lg);
    u32 ord = (u >> 31) ? ~u : (u | 0x80000000u);   // order-preserving map
    bool sel = (topmask[t] >> e) & 1u;
    key[j] = sel ? ord : 0u;                        // 0 == "not selected"
  }

  auto blockReduce = [&](u32 v) -> u32 {
#pragma unroll
    for (int off = 32; off; off >>= 1) v += __shfl_xor(v, off);
    if (lane == 0) wred[wv] = v;
    __syncthreads();
    if (tid == 0) { u32 s = 0; for (int i = 0; i < 16; ++i) s += wred[i]; bcast = s; }
    __syncthreads();
    u32 r = bcast;
    __syncthreads();
    return r;
  };

  u32 nsel = blockReduce((key[0] != 0u) + (key[1] != 0u) + (key[2] != 0u) + (key[3] != 0u));

  u32 p = 0, need = 0;
  if (nsel > CAPN) {
    need = CAPN;
    for (int b = 31; b >= 0; --b) {
      u32 cand = p | (1u << b);
      u32 hi = ~((1u << b) - 1u);
      u32 loc = 0;
#pragma unroll
      for (int j = 0; j < 4; ++j) loc += ((key[j] & hi) == cand) ? 1u : 0u;
      u32 c = blockReduce(loc);
      if (c >= need) p = cand; else need -= c;
    }
  }

  auto blockExScan = [&](u32 v, u32& total) -> u32 {
    u32 x = v;
#pragma unroll
    for (int off = 1; off < 64; off <<= 1) { u32 y = __shfl_up(x, off); if (lane >= off) x += y; }
    if (lane == 63) wscan[wv] = x;
    __syncthreads();
    if (wv == 0) {
      u32 w = (lane < 16) ? wscan[lane] : 0u;
#pragma unroll
      for (int off = 1; off < 16; off <<= 1) { u32 y = __shfl_up(w, off); if (lane >= off) w += y; }
      if (lane < 16) wscan[lane] = w;
    }
    __syncthreads();
    u32 base = wv ? wscan[wv - 1] : 0u;
    total = wscan[15];
    __syncthreads();
    return base + x - v;
  };

  bool eq[4], kept[4];
  u32 eqc = 0;
#pragma unroll
  for (int j = 0; j < 4; ++j) { eq[j] = (key[j] != 0u) && (key[j] == p); eqc += eq[j] ? 1u : 0u; }
  u32 eqtot;
  u32 eqbase = blockExScan(eqc, eqtot);
  u32 keptc = 0;
  {
    u32 er = eqbase;
#pragma unroll
    for (int j = 0; j < 4; ++j) {
      kept[j] = (key[j] != 0u) && ((key[j] > p) || (eq[j] && er < need));
      er += eq[j] ? 1u : 0u;
      keptc += kept[j] ? 1u : 0u;
    }
  }
  u32 ktot;
  u32 kbase = blockExScan(keptc, ktot);
  {
    u32 slot = kbase;
#pragma unroll
    for (int j = 0; j < 4; ++j) {
      if (kept[j]) {
        int t = tid * 4 + j;
        expert_tokens[e * CAPN + slot] = t;
        atomicOr(&keptmask[t], 1u << e);
        slot++;
      }
    }
  }
  for (u32 i = ktot + tid; i < CAPN; i += 1024) expert_tokens[e * CAPN + i] = -1;
}

// ---------- K3: rho + residual-rescale init of out, 4 tokens per block ----------
__global__ __launch_bounds__(256) void rho_init_kernel(
    const float* __restrict__ h, const float* __restrict__ logits,
    const u32* __restrict__ keptmask, float* __restrict__ out)
{
  const int t = blockIdx.x * 4 + (threadIdx.x >> 6);
  const int lane = threadIdx.x & 63;
  float v[NE]; float m = -3.4e38f;
#pragma unroll
  for (int i = 0; i < NE; ++i) { v[i] = logits[(size_t)t * NE + i]; m = fmaxf(m, v[i]); }
  float sum = 0.f;
#pragma unroll
  for (int i = 0; i < NE; ++i) { v[i] = expf(v[i] - m); sum += v[i]; }
  u32 km = keptmask[t];
  float rho = 0.f;
#pragma unroll
  for (int i = 0; i < NE; ++i) if ((km >> i) & 1u) rho += v[i];
  rho /= sum;
  float s = 1.0f - rho;
  const float4* hp4 = (const float4*)(h + (size_t)t * DIM);
  float4* op4 = (float4*)(out + (size_t)t * DIM);
#pragma unroll
  for (int i = 0; i < 4; ++i) {
    const float4 hv = hp4[lane + 64 * i];
    float4 o; o.x = hv.x * s; o.y = hv.y * s; o.z = hv.z * s; o.w = hv.w * s;
    op4[lane + 64 * i] = o;
  }
}

// ---------- K5: gather kept token rows -> bf16, + fused combine-weight (4 slots/block) ----------
__global__ __launch_bounds__(256) void gather_kernel(
    const float* __restrict__ h, const int* __restrict__ expert_tokens,
    const float* __restrict__ logits, u16* __restrict__ Xg, float* __restrict__ w_ec)
{
  const int slot = blockIdx.x * 4 + (threadIdx.x >> 6);
  const int lane = threadIdx.x & 63;
  const int t = expert_tokens[slot];
  u16* dst = Xg + (size_t)slot * DIM + lane * 16;
  if (t < 0) {
    if (lane == 0) w_ec[slot] = 0.f;
    uint4 z = make_uint4(0, 0, 0, 0);
    *(uint4*)dst = z; *(uint4*)(dst + 8) = z;
  } else {
    if (lane == 0) {
      const int e = slot / CAPN;
      float v[NE], m = -3.4e38f;
#pragma unroll
      for (int i = 0; i < NE; ++i) { v[i] = logits[(size_t)t * NE + i]; m = fmaxf(m, v[i]); }
      float sum = 0.f;
#pragma unroll
      for (int i = 0; i < NE; ++i) { v[i] = expf(v[i] - m); sum += v[i]; }
      w_ec[slot] = v[e] / sum;
    }
    const float4* src = (const float4*)(h + (size_t)t * DIM + lane * 16);
    __align__(16) u16 tmp[16];
#pragma unroll
    for (int q = 0; q < 4; ++q) {
      float4 x = src[q];
      tmp[q*4+0] = f2bf(x.x); tmp[q*4+1] = f2bf(x.y);
      tmp[q*4+2] = f2bf(x.z); tmp[q*4+3] = f2bf(x.w);
    }
    *(uint4*)dst = *(const uint4*)tmp;
    *(uint4*)(dst + 8) = *(const uint4*)(tmp + 8);
  }
}

// ---------- K6/K7: bf16 MFMA GEMM, fused f32->bf16 B-conversion, 512x64 tiles ----------
// r13/r17 sync structure (__syncthreads per K-step, depth-2 reg prefetch brE/brO,
// gll16 A, cvt_pk writeB, counted-lgkmcnt compute, XCD remap). ONE change vs r17:
// tile M 256->512 (whole expert), N 128->64. Each B panel now read by EXACTLY ONE
// block (B = read-once, minimal HBM/L3 traffic; was 2x). A doubles but is L2-resident
// (2MB per XCD's 2 experts). Per-wave work unchanged: 8 waves, wave grid 8Mx1N,
// per-wave 64x64 out, acc[4][4], 32 MFMA/step. LDS: A 2x64K + B 2x8K = 144KB.
// Register pressure DROPS (brE/brO halve to 2 float4).
#define LDS_TOTAL 147456

template <int EPI>
__global__ __launch_bounds__(512) void gemm_fused_kernel(
    const u16* __restrict__ Abase, const float* __restrict__ Bf32base,
    u16* __restrict__ Hout, float* __restrict__ out,
    const int* __restrict__ expert_tokens, const float* __restrict__ w_ec)
{
  extern __shared__ __align__(16) char smem[];
  char* As = smem;                 // 2 x 65536
  char* Bs = smem + 131072;        // 2 x 8192

  // XCD-aware remap: 256 blocks, bijective; each XCD owns 2 consecutive experts
  const int p   = blockIdx.x + 16 * blockIdx.z;
  const int lin = (p & 7) * 32 + (p >> 3);
  const int e   = lin >> 4;
  const int rem = lin & 15;
  const int n0  = rem * 64;        // m0 == 0 (whole expert in M)

  const char*  A = (const char*)(Abase + (size_t)e * 512 * 1024);
  const float* B = Bf32base + (size_t)e * 1024 * 1024;

  const int tid = threadIdx.x;
  const int lane = tid & 63, wave = tid >> 6;      // wave 0..7 = M-row block
  f32x4 acc[4][4];
#pragma unroll
  for (int i = 0; i < 4; ++i)
#pragma unroll
    for (int j = 0; j < 4; ++j) acc[i][j] = (f32x4){0.f, 0.f, 0.f, 0.f};

  const int srow  = lane >> 3;
  const int sbyte = 16 * ((lane & 7) ^ srow);
  const u32 asBase = (u32)(uintptr_t)As;
  const u32 bsTr0 = (u32)(uintptr_t)Bs + (u32)((lane >> 4) * 128 + (lane & 15) * 8);

  auto stageA = [&](int kt, int buf) {
    const int kb0 = kt * 128;
#pragma unroll
    for (int i = 0; i < 8; ++i) {
      const int c = wave * 8 + i;                  // 0..63 chunks of 8 rows
      const int r = c * 8 + srow;                  // 0..511
      gll16(As + buf * 65536 + c * 1024, A + (size_t)r * 2048 + kb0 + sbyte);
    }
  };
  auto loadB = [&](float4* br, int kt) {           // B tile: [64 k][64 n] f32 = 16 KB
    const int k0 = kt * 64;
    const int kl = tid >> 3, n8 = tid & 7;
    const float* gp = B + (size_t)(k0 + kl) * 1024 + n0 + n8 * 8;
    br[0] = *(const float4*)gp;
    br[1] = *(const float4*)(gp + 4);
  };
  auto writeB = [&](const float4* br, int buf) {
    const int kl = tid >> 3, n8 = tid & 7;
    const int c = (n8 >> 1) * 2 + ((kl >> 2) & 1); // 0..7 panels
    const int byt = c * 1024 + (kl >> 3) * 128 + (kl & 3) * 32 + (n8 & 1) * 16;
    const float* f = (const float*)br;
    u32 d[4];
#pragma unroll
    for (int j = 0; j < 4; ++j) {
      __hip_bfloat162 pk = __float22bfloat162_rn(make_float2(f[2*j], f[2*j+1]));
      d[j] = *(const u32*)&pk;
    }
    *(uint4*)(Bs + buf * 8192 + byt) = *(const uint4*)d;
  };
  auto compute = [&](int buf) {
#pragma unroll
    for (int s = 0; s < 2; ++s) {
      const int kb = (s * 64 + (lane >> 4) * 16) ^ ((lane & 7) << 4);
      bf16x8 af[4];
      unsigned long long tlo[4], thi[4];
#pragma unroll
      for (int i = 0; i < 4; ++i) {
        const int rowa = wave * 64 + i * 16 + (lane & 15);   // 0..511
        const u32 aaddr = asBase + (u32)(buf * 65536 + rowa * 128 + kb);
        asm volatile("ds_read_b128 %0, %1" : "=v"(af[i]) : "v"(aaddr) : "memory");
      }
#pragma unroll
      for (int j = 0; j < 4; ++j) {                // nb = j (per-wave N = full 64)
        const u32 a = bsTr0 + (u32)(buf * 8192 + j * 2048 + s * 512);
        asm volatile("ds_read_b64_tr_b16 %0, %2 offset:0\n\t"
                     "ds_read_b64_tr_b16 %1, %2 offset:1024"
                     : "=v"(tlo[j]), "=v"(thi[j]) : "v"(a) : "memory");
      }
#pragma unroll
      for (int j = 0; j < 4; ++j) {
        if (j == 0)      asm volatile("s_waitcnt lgkmcnt(6)" ::: "memory");
        else if (j == 1) asm volatile("s_waitcnt lgkmcnt(4)" ::: "memory");
        else if (j == 2) asm volatile("s_waitcnt lgkmcnt(2)" ::: "memory");
        else             asm volatile("s_waitcnt lgkmcnt(0)" ::: "memory");
        __builtin_amdgcn_sched_barrier(0);
        union { unsigned long long q[2]; bf16x8 v; } u;
        u.q[0] = tlo[j]; u.q[1] = thi[j];
        const bf16x8 bfv = u.v;
#pragma unroll
        for (int i = 0; i < 4; ++i)
          acc[i][j] = __builtin_amdgcn_mfma_f32_16x16x32_bf16(af[i], bfv, acc[i][j], 0, 0, 0);
      }
    }
  };

  // prologue: tile 0 staged directly; tile 1's B loads issued early (depth-2 pipe)
  stageA(0, 0);
  {
    float4 br0[2];
    loadB(br0, 0);
    writeB(br0, 0);
  }
  float4 brE[2], brO[2];
  loadB(brO, 1);                 // in flight across compute(kt=0)
  __syncthreads();

  // manually 2-unrolled K loop: tile kt lives in buf kt&1; all br indexing static
  for (int kt = 0; kt < 16; kt += 2) {
    // even step: cur buf 0, next buf 1 (tile kt+1, data in brO)
    if (kt + 2 < 16) loadB(brE, kt + 2);
    if (kt + 1 < 16) stageA(kt + 1, 1);
    compute(0);
    if (kt + 1 < 16) writeB(brO, 1);
    __syncthreads();
    if (kt + 1 < 16) {
      // odd step: cur buf 1, next buf 0 (tile kt+2, data in brE)
      if (kt + 3 < 16) loadB(brO, kt + 3);
      if (kt + 2 < 16) stageA(kt + 2, 0);
      compute(1);
      if (kt + 2 < 16) writeB(brE, 0);
      __syncthreads();
    }
  }

  if (EPI == 1) {
#pragma unroll
    for (int i = 0; i < 4; ++i) {
#pragma unroll
      for (int r = 0; r < 4; ++r) {
        const int row = wave * 64 + i * 16 + (lane >> 4) * 4 + r;
        u16* hp = Hout + ((size_t)e * 512 + row) * 1024 + n0 + (lane & 15);
#pragma unroll
        for (int j = 0; j < 4; ++j) hp[j * 16] = f2bf(gelu_tanh(acc[i][j][r]));
      }
    }
  } else {
#pragma unroll
    for (int i = 0; i < 4; ++i) {
#pragma unroll
      for (int r = 0; r < 4; ++r) {
        const int row  = wave * 64 + i * 16 + (lane >> 4) * 4 + r;
        const int slot = e * CAPN + row;
        const int t = expert_tokens[slot];
        if (t >= 0) {
          const float w = w_ec[slot];
          float* op = out + (size_t)t * DIM + n0 + (lane & 15);
#pragma unroll
          for (int j = 0; j < 4; ++j) atomicAdd(op + j * 16, acc[i][j][r] * w);
        }
      }
    }
  }
}

// ---------- launch ----------
extern "C" void kernel_launch(void* const* d_in, const int* in_sizes, int n_in,
                              void* d_out, int out_size, void* d_ws, size_t ws_size,
                              hipStream_t stream)
{
  const float* h  = (const float*)d_in[0];
  const float* Wr = (const float*)d_in[1];
  const float* W1 = (const float*)d_in[2];
  const float* W2 = (const float*)d_in[3];
  float* out = (float*)d_out;

  char* ws = (char*)d_ws;
  u16* Xg  = (u16*)(ws);                          // 16777216 B
  u16* Hb  = (u16*)(ws + 16777216);               // 16777216 B
  float* logits       = (float*)(ws + 33554432);  // 262144 B
  u32*   topmask      = (u32*)  (ws + 33816576);  // 16384 B
  u32*   keptmask     = (u32*)  (ws + 33832960);  // 16384 B
  int*   expert_tokens= (int*)  (ws + 33849344);  // 32768 B
  float* w_ec         = (float*)(ws + 33882112);  // 32768 B

  // allow >64KB dynamic LDS (gfx950: 160KB/WG); host-side attribute set (r6-proven path)
  (void)hipFuncSetAttribute(reinterpret_cast<const void*>(&gemm_fused_kernel<1>),
                            hipFuncAttributeMaxDynamicSharedMemorySize, LDS_TOTAL);
  (void)hipFuncSetAttribute(reinterpret_cast<const void*>(&gemm_fused_kernel<2>),
                            hipFuncAttributeMaxDynamicSharedMemorySize, LDS_TOTAL);

  router_kernel<<<T_TOK / 4, 256, 0, stream>>>(h, Wr, logits, topmask, keptmask);
  capacity_kernel<<<NE, 1024, 0, stream>>>(logits, topmask, keptmask, expert_tokens);
  rho_init_kernel<<<T_TOK / 4, 256, 0, stream>>>(h, logits, keptmask, out);
  gather_kernel<<<NE * CAPN / 4, 256, 0, stream>>>(h, expert_tokens, logits, Xg, w_ec);
  gemm_fused_kernel<1><<<dim3(16, 1, NE), 512, LDS_TOTAL, stream>>>(Xg, W1, Hb, nullptr, nullptr, nullptr);
  gemm_fused_kernel<2><<<dim3(16, 1, NE), 512, LDS_TOTAL, stream>>>(Hb, W2, nullptr, out, expert_tokens, w_ec);
}

// Round 19
// 137.908 us; speedup vs baseline: 1.0313x; 1.0313x over previous
//
#include <hip/hip_runtime.h>
#include <hip/hip_bf16.h>
#include <stdint.h>

#define T_TOK 4096
#define DIM   1024
#define NE    16
#define NDFF  1024
#define CAPN  512

typedef unsigned int   u32;
typedef unsigned short u16;
typedef __attribute__((ext_vector_type(8))) short bf16x8;
typedef __attribute__((ext_vector_type(4))) float f32x4;

// ---------- helpers ----------
__device__ __forceinline__ void gll16(void* lds, const void* g) {
  union { const void* p; const __attribute__((address_space(1))) void* q; } gu;
  union { void* p; __attribute__((address_space(3))) void* q; } lu;
  gu.p = g; lu.p = lds;
  __builtin_amdgcn_global_load_lds(gu.q, lu.q, 16, 0, 0);
}

__device__ __forceinline__ u16 f2bf(float f) {
  u32 u = __float_as_uint(f);
  u32 r = (u + 0x7FFFu + ((u >> 16) & 1u)) >> 16;   // RNE
  return (u16)r;
}

// gelu tanh-approx with fast exp: tanh(z) = 1 - 2/(e^{2z}+1)  (inf-safe both ends)
__device__ __forceinline__ float gelu_tanh(float x) {
  float x3 = x * x * x;
  float z = 0.7978845608028654f * (x + 0.044715f * x3);
  float t = __expf(2.0f * z);
  float th = 1.0f - 2.0f / (t + 1.0f);
  return 0.5f * x * (1.0f + th);
}

// ---------- K1: router (f32 exact), 4 tokens per 256-thr block ----------
__global__ __launch_bounds__(256) void router_kernel(
    const float* __restrict__ h, const float* __restrict__ Wr,
    float* __restrict__ logits, u32* __restrict__ topmask, u32* __restrict__ keptmask)
{
  const int t = blockIdx.x * 4 + (threadIdx.x >> 6);
  const int lane = threadIdx.x & 63;
  float acc[NE];
#pragma unroll
  for (int e = 0; e < NE; ++e) acc[e] = 0.f;
  const float* hrow = h + (size_t)t * DIM;
#pragma unroll 4
  for (int i = 0; i < DIM / 64; ++i) {
    int d = lane + 64 * i;
    float hv = hrow[d];
    const float4* wr4 = (const float4*)(Wr + (size_t)d * NE);
#pragma unroll
    for (int q = 0; q < 4; ++q) {
      float4 w = wr4[q];
      acc[q*4+0] += hv * w.x; acc[q*4+1] += hv * w.y;
      acc[q*4+2] += hv * w.z; acc[q*4+3] += hv * w.w;
    }
  }
#pragma unroll
  for (int e = 0; e < NE; ++e) {
    float v = acc[e];
#pragma unroll
    for (int off = 32; off; off >>= 1) v += __shfl_xor(v, off);
    acc[e] = v;
  }
  int m1 = 0; float b1 = acc[0];
#pragma unroll
  for (int e = 1; e < NE; ++e) if (acc[e] > b1) { b1 = acc[e]; m1 = e; }
  int m2 = 0; float b2 = -3.4e38f;
#pragma unroll
  for (int e = 0; e < NE; ++e) if (e != m1 && acc[e] > b2) { b2 = acc[e]; m2 = e; }
  if (lane < NE) logits[(size_t)t * NE + lane] = acc[lane];
  if (lane == 0) { topmask[t] = (1u << m1) | (1u << m2); keptmask[t] = 0u; }
}

// ---------- K2: per-expert capacity selection (exact, tie=lower index) ----------
__global__ __launch_bounds__(1024) void capacity_kernel(
    const float* __restrict__ logits, const u32* __restrict__ topmask,
    u32* __restrict__ keptmask, int* __restrict__ expert_tokens)
{
  const int e = blockIdx.x;
  const int tid = threadIdx.x;
  const int lane = tid & 63, wv = tid >> 6;
  __shared__ u32 wred[16];
  __shared__ u32 wscan[16];
  __shared__ u32 bcast;

  u32 key[4];
#pragma unroll
  for (int j = 0; j < 4; ++j) {
    int t = tid * 4 + j;
    float lg = logits[(size_t)t * NE + e];
    u32 u = __float_as_uint(lg);
    u32 ord = (u >> 31) ? ~u : (u | 0x80000000u);   // order-preserving map
    bool sel = (topmask[t] >> e) & 1u;
    key[j] = sel ? ord : 0u;                        // 0 == "not selected"
  }

  auto blockReduce = [&](u32 v) -> u32 {
#pragma unroll
    for (int off = 32; off; off >>= 1) v += __shfl_xor(v, off);
    if (lane == 0) wred[wv] = v;
    __syncthreads();
    if (tid == 0) { u32 s = 0; for (int i = 0; i < 16; ++i) s += wred[i]; bcast = s; }
    __syncthreads();
    u32 r = bcast;
    __syncthreads();
    return r;
  };

  u32 nsel = blockReduce((key[0] != 0u) + (key[1] != 0u) + (key[2] != 0u) + (key[3] != 0u));

  u32 p = 0, need = 0;
  if (nsel > CAPN) {
    need = CAPN;
    for (int b = 31; b >= 0; --b) {
      u32 cand = p | (1u << b);
      u32 hi = ~((1u << b) - 1u);
      u32 loc = 0;
#pragma unroll
      for (int j = 0; j < 4; ++j) loc += ((key[j] & hi) == cand) ? 1u : 0u;
      u32 c = blockReduce(loc);
      if (c >= need) p = cand; else need -= c;
    }
  }

  auto blockExScan = [&](u32 v, u32& total) -> u32 {
    u32 x = v;
#pragma unroll
    for (int off = 1; off < 64; off <<= 1) { u32 y = __shfl_up(x, off); if (lane >= off) x += y; }
    if (lane == 63) wscan[wv] = x;
    __syncthreads();
    if (wv == 0) {
      u32 w = (lane < 16) ? wscan[lane] : 0u;
#pragma unroll
      for (int off = 1; off < 16; off <<= 1) { u32 y = __shfl_up(w, off); if (lane >= off) w += y; }
      if (lane < 16) wscan[lane] = w;
    }
    __syncthreads();
    u32 base = wv ? wscan[wv - 1] : 0u;
    total = wscan[15];
    __syncthreads();
    return base + x - v;
  };

  bool eq[4], kept[4];
  u32 eqc = 0;
#pragma unroll
  for (int j = 0; j < 4; ++j) { eq[j] = (key[j] != 0u) && (key[j] == p); eqc += eq[j] ? 1u : 0u; }
  u32 eqtot;
  u32 eqbase = blockExScan(eqc, eqtot);
  u32 keptc = 0;
  {
    u32 er = eqbase;
#pragma unroll
    for (int j = 0; j < 4; ++j) {
      kept[j] = (key[j] != 0u) && ((key[j] > p) || (eq[j] && er < need));
      er += eq[j] ? 1u : 0u;
      keptc += kept[j] ? 1u : 0u;
    }
  }
  u32 ktot;
  u32 kbase = blockExScan(keptc, ktot);
  {
    u32 slot = kbase;
#pragma unroll
    for (int j = 0; j < 4; ++j) {
      if (kept[j]) {
        int t = tid * 4 + j;
        expert_tokens[e * CAPN + slot] = t;
        atomicOr(&keptmask[t], 1u << e);
        slot++;
      }
    }
  }
  for (u32 i = ktot + tid; i < CAPN; i += 1024) expert_tokens[e * CAPN + i] = -1;
}

// ---------- K3: rho + residual-rescale init of out, 4 tokens per block ----------
__global__ __launch_bounds__(256) void rho_init_kernel(
    const float* __restrict__ h, const float* __restrict__ logits,
    const u32* __restrict__ keptmask, float* __restrict__ out)
{
  const int t = blockIdx.x * 4 + (threadIdx.x >> 6);
  const int lane = threadIdx.x & 63;
  float v[NE]; float m = -3.4e38f;
#pragma unroll
  for (int i = 0; i < NE; ++i) { v[i] = logits[(size_t)t * NE + i]; m = fmaxf(m, v[i]); }
  float sum = 0.f;
#pragma unroll
  for (int i = 0; i < NE; ++i) { v[i] = expf(v[i] - m); sum += v[i]; }
  u32 km = keptmask[t];
  float rho = 0.f;
#pragma unroll
  for (int i = 0; i < NE; ++i) if ((km >> i) & 1u) rho += v[i];
  rho /= sum;
  float s = 1.0f - rho;
  const float4* hp4 = (const float4*)(h + (size_t)t * DIM);
  float4* op4 = (float4*)(out + (size_t)t * DIM);
#pragma unroll
  for (int i = 0; i < 4; ++i) {
    const float4 hv = hp4[lane + 64 * i];
    float4 o; o.x = hv.x * s; o.y = hv.y * s; o.z = hv.z * s; o.w = hv.w * s;
    op4[lane + 64 * i] = o;
  }
}

// ---------- K5: gather kept token rows -> bf16, + fused combine-weight (4 slots/block) ----------
__global__ __launch_bounds__(256) void gather_kernel(
    const float* __restrict__ h, const int* __restrict__ expert_tokens,
    const float* __restrict__ logits, u16* __restrict__ Xg, float* __restrict__ w_ec)
{
  const int slot = blockIdx.x * 4 + (threadIdx.x >> 6);
  const int lane = threadIdx.x & 63;
  const int t = expert_tokens[slot];
  u16* dst = Xg + (size_t)slot * DIM + lane * 16;
  if (t < 0) {
    if (lane == 0) w_ec[slot] = 0.f;
    uint4 z = make_uint4(0, 0, 0, 0);
    *(uint4*)dst = z; *(uint4*)(dst + 8) = z;
  } else {
    if (lane == 0) {
      const int e = slot / CAPN;
      float v[NE], m = -3.4e38f;
#pragma unroll
      for (int i = 0; i < NE; ++i) { v[i] = logits[(size_t)t * NE + i]; m = fmaxf(m, v[i]); }
      float sum = 0.f;
#pragma unroll
      for (int i = 0; i < NE; ++i) { v[i] = expf(v[i] - m); sum += v[i]; }
      w_ec[slot] = v[e] / sum;
    }
    const float4* src = (const float4*)(h + (size_t)t * DIM + lane * 16);
    __align__(16) u16 tmp[16];
#pragma unroll
    for (int q = 0; q < 4; ++q) {
      float4 x = src[q];
      tmp[q*4+0] = f2bf(x.x); tmp[q*4+1] = f2bf(x.y);
      tmp[q*4+2] = f2bf(x.z); tmp[q*4+3] = f2bf(x.w);
    }
    *(uint4*)dst = *(const uint4*)tmp;
    *(uint4*)(dst + 8) = *(const uint4*)(tmp + 8);
  }
}

// ---------- K6/K7: bf16 MFMA GEMM, fused f32->bf16 B-conversion, 256x128 tiles ----------
// Byte-identical to the round-17 PASSING 137.2us kernel (256x128, 8 waves, depth-2 reg
// prefetch brE/brO, gll16 A, cvt_pk writeB, counted-lgkmcnt compute, XCD remap, 96 KB
// dynamic LDS, 1 block/CU, __syncthreads per K-step) EXCEPT the EPI==1 epilogue:
// stores previously wrote 2B-scattered (partial 64B lines -> 2x HBM write amplification,
// WRITE_SIZE 32MB for a 16MB output). New epilogue bounces each wave's 64x64 tile
// through a wave-PRIVATE 8KB LDS slice (no new barriers; lgkmcnt-only, rule 18), then
// emits full 128B-line stores (8 lanes x 16B per row, 8 rows per pass).
#define LDS_TOTAL 98304

template <int EPI>
__global__ __launch_bounds__(512) void gemm_fused_kernel(
    const u16* __restrict__ Abase, const float* __restrict__ Bf32base,
    u16* __restrict__ Hout, float* __restrict__ out,
    const int* __restrict__ expert_tokens, const float* __restrict__ w_ec)
{
  extern __shared__ __align__(16) char smem[];
  char* As = smem;                 // 2 x 32768
  char* Bs = smem + 65536;         // 2 x 16384

  // XCD-aware remap: 256 blocks, bijective; each XCD owns 2 consecutive experts
  const int p   = blockIdx.x + 8 * (blockIdx.y + 2 * blockIdx.z);
  const int lin = (p & 7) * 32 + (p >> 3);
  const int e   = lin >> 4;
  const int rem = lin & 15;
  const int m0  = (rem >> 3) * 256;
  const int n0  = (rem & 7) * 128;

  const char*  A = (const char*)(Abase + (size_t)e * 512 * 1024);
  const float* B = Bf32base + (size_t)e * 1024 * 1024;

  const int tid = threadIdx.x;
  const int lane = tid & 63, wave = tid >> 6;      // wave 0..7
  const int wr = wave >> 1, wc = wave & 1;         // 4Mx2N; per-wave 64x64 out
  f32x4 acc[4][4];
#pragma unroll
  for (int i = 0; i < 4; ++i)
#pragma unroll
    for (int j = 0; j < 4; ++j) acc[i][j] = (f32x4){0.f, 0.f, 0.f, 0.f};

  const int srow  = lane >> 3;
  const int sbyte = 16 * ((lane & 7) ^ srow);
  const u32 asBase = (u32)(uintptr_t)As;
  const u32 bsTr0 = (u32)(uintptr_t)Bs + (u32)((lane >> 4) * 128 + (lane & 15) * 8);

  auto stageA = [&](int kt, int buf) {
    const int kb0 = kt * 128;
#pragma unroll
    for (int i = 0; i < 4; ++i) {
      const int c = wave * 4 + i;                  // 0..31 chunks of 8 rows
      const int r = c * 8 + srow;                  // 0..255
      gll16(As + buf * 32768 + c * 1024, A + (size_t)(m0 + r) * 2048 + kb0 + sbyte);
    }
  };
  auto loadB = [&](float4* br, int kt) {
    const int k0 = kt * 64;
#pragma unroll
    for (int it = 0; it < 2; ++it) {
      const int q = tid + 512 * it;                // 0..1023
      const int kl = q >> 4, n8 = q & 15;
      const float* gp = B + (size_t)(k0 + kl) * 1024 + n0 + n8 * 8;
      br[2*it]   = *(const float4*)gp;
      br[2*it+1] = *(const float4*)(gp + 4);
    }
  };
  auto writeB = [&](const float4* br, int buf) {
#pragma unroll
    for (int it = 0; it < 2; ++it) {
      const int q = tid + 512 * it;
      const int kl = q >> 4, n8 = q & 15;
      const int c = (n8 >> 1) * 2 + ((kl >> 2) & 1);
      const int byt = c * 1024 + (kl >> 3) * 128 + (kl & 3) * 32 + (n8 & 1) * 16;
      const float* f = (const float*)&br[2*it];
      u32 d[4];
#pragma unroll
      for (int j = 0; j < 4; ++j) {
        __hip_bfloat162 pk = __float22bfloat162_rn(make_float2(f[2*j], f[2*j+1]));
        d[j] = *(const u32*)&pk;                   // low16 = f[2j]
      }
      *(uint4*)(Bs + buf * 16384 + byt) = *(const uint4*)d;
    }
  };
  auto compute = [&](int buf) {
#pragma unroll
    for (int s = 0; s < 2; ++s) {
      const int kb = (s * 64 + (lane >> 4) * 16) ^ ((lane & 7) << 4);
      bf16x8 af[4];
      unsigned long long tlo[4], thi[4];
      // issue 12 LDS reads in fixed order: A0..A3, then tr-pairs P0..P3
#pragma unroll
      for (int i = 0; i < 4; ++i) {
        const int rowa = wr * 64 + i * 16 + (lane & 15);
        const u32 aaddr = asBase + (u32)(buf * 32768 + rowa * 128 + kb);
        asm volatile("ds_read_b128 %0, %1" : "=v"(af[i]) : "v"(aaddr) : "memory");
      }
#pragma unroll
      for (int j = 0; j < 4; ++j) {
        const u32 a = bsTr0 + (u32)(buf * 16384 + (wc * 4 + j) * 2048 + s * 512);
        asm volatile("ds_read_b64_tr_b16 %0, %2 offset:0\n\t"
                     "ds_read_b64_tr_b16 %1, %2 offset:1024"
                     : "=v"(tlo[j]), "=v"(thi[j]) : "v"(a) : "memory");
      }
      // staged MFMA: wait counts per in-order completion (12 total reads)
#pragma unroll
      for (int j = 0; j < 4; ++j) {
        if (j == 0)      asm volatile("s_waitcnt lgkmcnt(6)" ::: "memory");
        else if (j == 1) asm volatile("s_waitcnt lgkmcnt(4)" ::: "memory");
        else if (j == 2) asm volatile("s_waitcnt lgkmcnt(2)" ::: "memory");
        else             asm volatile("s_waitcnt lgkmcnt(0)" ::: "memory");
        __builtin_amdgcn_sched_barrier(0);
        union { unsigned long long q[2]; bf16x8 v; } u;
        u.q[0] = tlo[j]; u.q[1] = thi[j];
        const bf16x8 bfv = u.v;
#pragma unroll
        for (int i = 0; i < 4; ++i)
          acc[i][j] = __builtin_amdgcn_mfma_f32_16x16x32_bf16(af[i], bfv, acc[i][j], 0, 0, 0);
      }
    }
  };

  // prologue: tile 0 staged directly; tile 1's B loads issued early (depth-2 pipe)
  stageA(0, 0);
  {
    float4 br0[4];
    loadB(br0, 0);
    writeB(br0, 0);
  }
  float4 brE[4], brO[4];
  loadB(brO, 1);                 // in flight across compute(kt=0)
  __syncthreads();

  // manually 2-unrolled K loop: tile kt lives in buf kt&1; all br indexing static
  for (int kt = 0; kt < 16; kt += 2) {
    // even step: cur buf 0, next buf 1 (tile kt+1, data in brO)
    if (kt + 2 < 16) loadB(brE, kt + 2);
    if (kt + 1 < 16) stageA(kt + 1, 1);
    compute(0);
    if (kt + 1 < 16) writeB(brO, 1);
    __syncthreads();
    if (kt + 1 < 16) {
      // odd step: cur buf 1, next buf 0 (tile kt+2, data in brE)
      if (kt + 3 < 16) loadB(brO, kt + 3);
      if (kt + 2 < 16) stageA(kt + 2, 0);
      compute(1);
      if (kt + 2 < 16) writeB(brE, 0);
      __syncthreads();
    }
  }

  if (EPI == 1) {
    // coalesced epilogue: wave-private 8KB LDS slice [64 rows][64 cols] u16
    char* eps = smem + wave * 8192;
#pragma unroll
    for (int i = 0; i < 4; ++i)
#pragma unroll
      for (int j = 0; j < 4; ++j)
#pragma unroll
        for (int r = 0; r < 4; ++r) {
          const int lrow = i * 16 + (lane >> 4) * 4 + r;
          const int lcol = j * 16 + (lane & 15);
          *(u16*)(eps + lrow * 128 + lcol * 2) = f2bf(gelu_tanh(acc[i][j][r]));
        }
    asm volatile("s_waitcnt lgkmcnt(0)" ::: "memory");   // wave-private: no barrier needed
#pragma unroll
    for (int pp = 0; pp < 8; ++pp) {
      const int lrow = pp * 8 + (lane >> 3);             // 8 rows per pass
      const int chnk = lane & 7;                         // 8 x 16B chunks = full 128B row
      uint4 d;
      const u32 ra = (u32)(uintptr_t)(eps + lrow * 128 + chnk * 16);
      asm volatile("ds_read_b128 %0, %1" : "=v"(d) : "v"(ra) : "memory");
      asm volatile("s_waitcnt lgkmcnt(0)" ::: "memory");
      const int grow = m0 + wr * 64 + lrow;
      *(uint4*)(Hout + ((size_t)e * 512 + grow) * 1024 + n0 + wc * 64 + chnk * 8) = d;
    }
  } else {
#pragma unroll
    for (int i = 0; i < 4; ++i) {
#pragma unroll
      for (int r = 0; r < 4; ++r) {
        const int row  = m0 + wr * 64 + i * 16 + (lane >> 4) * 4 + r;
        const int slot = e * CAPN + row;
        const int t = expert_tokens[slot];
        if (t >= 0) {
          const float w = w_ec[slot];
          float* op = out + (size_t)t * DIM + n0 + wc * 64 + (lane & 15);
#pragma unroll
          for (int j = 0; j < 4; ++j) atomicAdd(op + j * 16, acc[i][j][r] * w);
        }
      }
    }
  }
}

// ---------- launch ----------
extern "C" void kernel_launch(void* const* d_in, const int* in_sizes, int n_in,
                              void* d_out, int out_size, void* d_ws, size_t ws_size,
                              hipStream_t stream)
{
  const float* h  = (const float*)d_in[0];
  const float* Wr = (const float*)d_in[1];
  const float* W1 = (const float*)d_in[2];
  const float* W2 = (const float*)d_in[3];
  float* out = (float*)d_out;

  char* ws = (char*)d_ws;
  u16* Xg  = (u16*)(ws);                          // 16777216 B
  u16* Hb  = (u16*)(ws + 16777216);               // 16777216 B
  float* logits       = (float*)(ws + 33554432);  // 262144 B
  u32*   topmask      = (u32*)  (ws + 33816576);  // 16384 B
  u32*   keptmask     = (u32*)  (ws + 33832960);  // 16384 B
  int*   expert_tokens= (int*)  (ws + 33849344);  // 32768 B
  float* w_ec         = (float*)(ws + 33882112);  // 32768 B

  // allow >64KB dynamic LDS (gfx950: 160KB/WG); host-side attribute set (r6-proven path)
  (void)hipFuncSetAttribute(reinterpret_cast<const void*>(&gemm_fused_kernel<1>),
                            hipFuncAttributeMaxDynamicSharedMemorySize, LDS_TOTAL);
  (void)hipFuncSetAttribute(reinterpret_cast<const void*>(&gemm_fused_kernel<2>),
                            hipFuncAttributeMaxDynamicSharedMemorySize, LDS_TOTAL);

  router_kernel<<<T_TOK / 4, 256, 0, stream>>>(h, Wr, logits, topmask, keptmask);
  capacity_kernel<<<NE, 1024, 0, stream>>>(logits, topmask, keptmask, expert_tokens);
  rho_init_kernel<<<T_TOK / 4, 256, 0, stream>>>(h, logits, keptmask, out);
  gather_kernel<<<NE * CAPN / 4, 256, 0, stream>>>(h, expert_tokens, logits, Xg, w_ec);
  gemm_fused_kernel<1><<<dim3(8, 2, NE), 512, LDS_TOTAL, stream>>>(Xg, W1, Hb, nullptr, nullptr, nullptr);
  gemm_fused_kernel<2><<<dim3(8, 2, NE), 512, LDS_TOTAL, stream>>>(Hb, W2, nullptr, out, expert_tokens, w_ec);
}

// Round 20
// 133.996 us; speedup vs baseline: 1.0614x; 1.0292x over previous
//
#include <hip/hip_runtime.h>
#include <hip/hip_bf16.h>
#include <stdint.h>

#define T_TOK 4096
#define DIM   1024
#define NE    16
#define NDFF  1024
#define CAPN  512

typedef unsigned int   u32;
typedef unsigned short u16;
typedef __attribute__((ext_vector_type(8))) short bf16x8;
typedef __attribute__((ext_vector_type(4))) float f32x4;

// ---------- helpers ----------
__device__ __forceinline__ void gll16(void* lds, const void* g) {
  union { const void* p; const __attribute__((address_space(1))) void* q; } gu;
  union { void* p; __attribute__((address_space(3))) void* q; } lu;
  gu.p = g; lu.p = lds;
  __builtin_amdgcn_global_load_lds(gu.q, lu.q, 16, 0, 0);
}

__device__ __forceinline__ u16 f2bf(float f) {
  u32 u = __float_as_uint(f);
  u32 r = (u + 0x7FFFu + ((u >> 16) & 1u)) >> 16;   // RNE
  return (u16)r;
}

// gelu tanh-approx with fast exp: tanh(z) = 1 - 2/(e^{2z}+1)  (inf-safe both ends)
__device__ __forceinline__ float gelu_tanh(float x) {
  float x3 = x * x * x;
  float z = 0.7978845608028654f * (x + 0.044715f * x3);
  float t = __expf(2.0f * z);
  float th = 1.0f - 2.0f / (t + 1.0f);
  return 0.5f * x * (1.0f + th);
}

// ---------- K1: router (f32 exact), 4 tokens per 256-thr block ----------
__global__ __launch_bounds__(256) void router_kernel(
    const float* __restrict__ h, const float* __restrict__ Wr,
    float* __restrict__ logits, u32* __restrict__ topmask, u32* __restrict__ keptmask)
{
  const int t = blockIdx.x * 4 + (threadIdx.x >> 6);
  const int lane = threadIdx.x & 63;
  float acc[NE];
#pragma unroll
  for (int e = 0; e < NE; ++e) acc[e] = 0.f;
  const float* hrow = h + (size_t)t * DIM;
#pragma unroll 4
  for (int i = 0; i < DIM / 64; ++i) {
    int d = lane + 64 * i;
    float hv = hrow[d];
    const float4* wr4 = (const float4*)(Wr + (size_t)d * NE);
#pragma unroll
    for (int q = 0; q < 4; ++q) {
      float4 w = wr4[q];
      acc[q*4+0] += hv * w.x; acc[q*4+1] += hv * w.y;
      acc[q*4+2] += hv * w.z; acc[q*4+3] += hv * w.w;
    }
  }
#pragma unroll
  for (int e = 0; e < NE; ++e) {
    float v = acc[e];
#pragma unroll
    for (int off = 32; off; off >>= 1) v += __shfl_xor(v, off);
    acc[e] = v;
  }
  int m1 = 0; float b1 = acc[0];
#pragma unroll
  for (int e = 1; e < NE; ++e) if (acc[e] > b1) { b1 = acc[e]; m1 = e; }
  int m2 = 0; float b2 = -3.4e38f;
#pragma unroll
  for (int e = 0; e < NE; ++e) if (e != m1 && acc[e] > b2) { b2 = acc[e]; m2 = e; }
  if (lane < NE) logits[(size_t)t * NE + lane] = acc[lane];
  if (lane == 0) { topmask[t] = (1u << m1) | (1u << m2); keptmask[t] = 0u; }
}

// ---------- K2: per-expert capacity selection (exact, tie=lower index) ----------
__global__ __launch_bounds__(1024) void capacity_kernel(
    const float* __restrict__ logits, const u32* __restrict__ topmask,
    u32* __restrict__ keptmask, int* __restrict__ expert_tokens)
{
  const int e = blockIdx.x;
  const int tid = threadIdx.x;
  const int lane = tid & 63, wv = tid >> 6;
  __shared__ u32 wred[16];
  __shared__ u32 wscan[16];
  __shared__ u32 bcast;

  u32 key[4];
#pragma unroll
  for (int j = 0; j < 4; ++j) {
    int t = tid * 4 + j;
    float lg = logits[(size_t)t * NE + e];
    u32 u = __float_as_uint(lg);
    u32 ord = (u >> 31) ? ~u : (u | 0x80000000u);   // order-preserving map
    bool sel = (topmask[t] >> e) & 1u;
    key[j] = sel ? ord : 0u;                        // 0 == "not selected"
  }

  auto blockReduce = [&](u32 v) -> u32 {
#pragma unroll
    for (int off = 32; off; off >>= 1) v += __shfl_xor(v, off);
    if (lane == 0) wred[wv] = v;
    __syncthreads();
    if (tid == 0) { u32 s = 0; for (int i = 0; i < 16; ++i) s += wred[i]; bcast = s; }
    __syncthreads();
    u32 r = bcast;
    __syncthreads();
    return r;
  };

  u32 nsel = blockReduce((key[0] != 0u) + (key[1] != 0u) + (key[2] != 0u) + (key[3] != 0u));

  u32 p = 0, need = 0;
  if (nsel > CAPN) {
    need = CAPN;
    for (int b = 31; b >= 0; --b) {
      u32 cand = p | (1u << b);
      u32 hi = ~((1u << b) - 1u);
      u32 loc = 0;
#pragma unroll
      for (int j = 0; j < 4; ++j) loc += ((key[j] & hi) == cand) ? 1u : 0u;
      u32 c = blockReduce(loc);
      if (c >= need) p = cand; else need -= c;
    }
  }

  auto blockExScan = [&](u32 v, u32& total) -> u32 {
    u32 x = v;
#pragma unroll
    for (int off = 1; off < 64; off <<= 1) { u32 y = __shfl_up(x, off); if (lane >= off) x += y; }
    if (lane == 63) wscan[wv] = x;
    __syncthreads();
    if (wv == 0) {
      u32 w = (lane < 16) ? wscan[lane] : 0u;
#pragma unroll
      for (int off = 1; off < 16; off <<= 1) { u32 y = __shfl_up(w, off); if (lane >= off) w += y; }
      if (lane < 16) wscan[lane] = w;
    }
    __syncthreads();
    u32 base = wv ? wscan[wv - 1] : 0u;
    total = wscan[15];
    __syncthreads();
    return base + x - v;
  };

  bool eq[4], kept[4];
  u32 eqc = 0;
#pragma unroll
  for (int j = 0; j < 4; ++j) { eq[j] = (key[j] != 0u) && (key[j] == p); eqc += eq[j] ? 1u : 0u; }
  u32 eqtot;
  u32 eqbase = blockExScan(eqc, eqtot);
  u32 keptc = 0;
  {
    u32 er = eqbase;
#pragma unroll
    for (int j = 0; j < 4; ++j) {
      kept[j] = (key[j] != 0u) && ((key[j] > p) || (eq[j] && er < need));
      er += eq[j] ? 1u : 0u;
      keptc += kept[j] ? 1u : 0u;
    }
  }
  u32 ktot;
  u32 kbase = blockExScan(keptc, ktot);
  {
    u32 slot = kbase;
#pragma unroll
    for (int j = 0; j < 4; ++j) {
      if (kept[j]) {
        int t = tid * 4 + j;
        expert_tokens[e * CAPN + slot] = t;
        atomicOr(&keptmask[t], 1u << e);
        slot++;
      }
    }
  }
  for (u32 i = ktot + tid; i < CAPN; i += 1024) expert_tokens[e * CAPN + i] = -1;
}

// ---------- K3: merged prep = rho_init (blocks 0..1023) + gather (blocks 1024..3071) ----------
__global__ __launch_bounds__(256) void prep_kernel(
    const float* __restrict__ h, const float* __restrict__ logits,
    const u32* __restrict__ keptmask, const int* __restrict__ expert_tokens,
    float* __restrict__ out, u16* __restrict__ Xg, float* __restrict__ w_ec)
{
  const int lane = threadIdx.x & 63;
  if (blockIdx.x < T_TOK / 4) {
    // ---- rho + residual-rescale init of out (4 tokens/block) ----
    const int t = blockIdx.x * 4 + (threadIdx.x >> 6);
    float v[NE]; float m = -3.4e38f;
#pragma unroll
    for (int i = 0; i < NE; ++i) { v[i] = logits[(size_t)t * NE + i]; m = fmaxf(m, v[i]); }
    float sum = 0.f;
#pragma unroll
    for (int i = 0; i < NE; ++i) { v[i] = expf(v[i] - m); sum += v[i]; }
    u32 km = keptmask[t];
    float rho = 0.f;
#pragma unroll
    for (int i = 0; i < NE; ++i) if ((km >> i) & 1u) rho += v[i];
    rho /= sum;
    float s = 1.0f - rho;
    const float4* hp4 = (const float4*)(h + (size_t)t * DIM);
    float4* op4 = (float4*)(out + (size_t)t * DIM);
#pragma unroll
    for (int i = 0; i < 4; ++i) {
      const float4 hv = hp4[lane + 64 * i];
      float4 o; o.x = hv.x * s; o.y = hv.y * s; o.z = hv.z * s; o.w = hv.w * s;
      op4[lane + 64 * i] = o;
    }
  } else {
    // ---- gather kept token rows -> bf16, + fused combine weight (4 slots/block) ----
    const int slot = (blockIdx.x - T_TOK / 4) * 4 + (threadIdx.x >> 6);
    const int t = expert_tokens[slot];
    u16* dst = Xg + (size_t)slot * DIM + lane * 16;
    if (t < 0) {
      if (lane == 0) w_ec[slot] = 0.f;
      uint4 z = make_uint4(0, 0, 0, 0);
      *(uint4*)dst = z; *(uint4*)(dst + 8) = z;
    } else {
      if (lane == 0) {
        const int e = slot / CAPN;
        float v[NE], m = -3.4e38f;
#pragma unroll
        for (int i = 0; i < NE; ++i) { v[i] = logits[(size_t)t * NE + i]; m = fmaxf(m, v[i]); }
        float sum = 0.f;
#pragma unroll
        for (int i = 0; i < NE; ++i) { v[i] = expf(v[i] - m); sum += v[i]; }
        w_ec[slot] = v[e] / sum;
      }
      const float4* src = (const float4*)(h + (size_t)t * DIM + lane * 16);
      __align__(16) u16 tmp[16];
#pragma unroll
      for (int q = 0; q < 4; ++q) {
        float4 x = src[q];
        tmp[q*4+0] = f2bf(x.x); tmp[q*4+1] = f2bf(x.y);
        tmp[q*4+2] = f2bf(x.z); tmp[q*4+3] = f2bf(x.w);
      }
      *(uint4*)dst = *(const uint4*)tmp;
      *(uint4*)(dst + 8) = *(const uint4*)(tmp + 8);
    }
  }
}

// ---------- K6/K7: bf16 MFMA GEMM, fused f32->bf16 B-conversion, 256x128 tiles ----------
// Byte-identical GEMM core to the r17/r19 PASSING kernels (best total 137.2us):
// 256x128 tile, 8 waves, depth-2 reg prefetch brE/brO, gll16 A, cvt_pk writeB,
// counted-lgkmcnt compute, XCD remap, 96 KB dynamic LDS, __syncthreads per K-step.
// EPI==2 change only: expert_tokens/w_ec epilogue loads hoisted before the final
// compute so their global-load latency hides under the last 32 MFMAs.
#define LDS_TOTAL 98304

template <int EPI>
__global__ __launch_bounds__(512) void gemm_fused_kernel(
    const u16* __restrict__ Abase, const float* __restrict__ Bf32base,
    u16* __restrict__ Hout, float* __restrict__ out,
    const int* __restrict__ expert_tokens, const float* __restrict__ w_ec)
{
  extern __shared__ __align__(16) char smem[];
  char* As = smem;                 // 2 x 32768
  char* Bs = smem + 65536;         // 2 x 16384

  // XCD-aware remap: 256 blocks, bijective; each XCD owns 2 consecutive experts
  const int p   = blockIdx.x + 8 * (blockIdx.y + 2 * blockIdx.z);
  const int lin = (p & 7) * 32 + (p >> 3);
  const int e   = lin >> 4;
  const int rem = lin & 15;
  const int m0  = (rem >> 3) * 256;
  const int n0  = (rem & 7) * 128;

  const char*  A = (const char*)(Abase + (size_t)e * 512 * 1024);
  const float* B = Bf32base + (size_t)e * 1024 * 1024;

  const int tid = threadIdx.x;
  const int lane = tid & 63, wave = tid >> 6;      // wave 0..7
  const int wr = wave >> 1, wc = wave & 1;         // 4Mx2N; per-wave 64x64 out
  f32x4 acc[4][4];
#pragma unroll
  for (int i = 0; i < 4; ++i)
#pragma unroll
    for (int j = 0; j < 4; ++j) acc[i][j] = (f32x4){0.f, 0.f, 0.f, 0.f};

  const int srow  = lane >> 3;
  const int sbyte = 16 * ((lane & 7) ^ srow);
  const u32 asBase = (u32)(uintptr_t)As;
  const u32 bsTr0 = (u32)(uintptr_t)Bs + (u32)((lane >> 4) * 128 + (lane & 15) * 8);

  auto stageA = [&](int kt, int buf) {
    const int kb0 = kt * 128;
#pragma unroll
    for (int i = 0; i < 4; ++i) {
      const int c = wave * 4 + i;                  // 0..31 chunks of 8 rows
      const int r = c * 8 + srow;                  // 0..255
      gll16(As + buf * 32768 + c * 1024, A + (size_t)(m0 + r) * 2048 + kb0 + sbyte);
    }
  };
  auto loadB = [&](float4* br, int kt) {
    const int k0 = kt * 64;
#pragma unroll
    for (int it = 0; it < 2; ++it) {
      const int q = tid + 512 * it;                // 0..1023
      const int kl = q >> 4, n8 = q & 15;
      const float* gp = B + (size_t)(k0 + kl) * 1024 + n0 + n8 * 8;
      br[2*it]   = *(const float4*)gp;
      br[2*it+1] = *(const float4*)(gp + 4);
    }
  };
  auto writeB = [&](const float4* br, int buf) {
#pragma unroll
    for (int it = 0; it < 2; ++it) {
      const int q = tid + 512 * it;
      const int kl = q >> 4, n8 = q & 15;
      const int c = (n8 >> 1) * 2 + ((kl >> 2) & 1);
      const int byt = c * 1024 + (kl >> 3) * 128 + (kl & 3) * 32 + (n8 & 1) * 16;
      const float* f = (const float*)&br[2*it];
      u32 d[4];
#pragma unroll
      for (int j = 0; j < 4; ++j) {
        __hip_bfloat162 pk = __float22bfloat162_rn(make_float2(f[2*j], f[2*j+1]));
        d[j] = *(const u32*)&pk;                   // low16 = f[2j]
      }
      *(uint4*)(Bs + buf * 16384 + byt) = *(const uint4*)d;
    }
  };
  auto compute = [&](int buf) {
#pragma unroll
    for (int s = 0; s < 2; ++s) {
      const int kb = (s * 64 + (lane >> 4) * 16) ^ ((lane & 7) << 4);
      bf16x8 af[4];
      unsigned long long tlo[4], thi[4];
      // issue 12 LDS reads in fixed order: A0..A3, then tr-pairs P0..P3
#pragma unroll
      for (int i = 0; i < 4; ++i) {
        const int rowa = wr * 64 + i * 16 + (lane & 15);
        const u32 aaddr = asBase + (u32)(buf * 32768 + rowa * 128 + kb);
        asm volatile("ds_read_b128 %0, %1" : "=v"(af[i]) : "v"(aaddr) : "memory");
      }
#pragma unroll
      for (int j = 0; j < 4; ++j) {
        const u32 a = bsTr0 + (u32)(buf * 16384 + (wc * 4 + j) * 2048 + s * 512);
        asm volatile("ds_read_b64_tr_b16 %0, %2 offset:0\n\t"
                     "ds_read_b64_tr_b16 %1, %2 offset:1024"
                     : "=v"(tlo[j]), "=v"(thi[j]) : "v"(a) : "memory");
      }
      // staged MFMA: wait counts per in-order completion (12 total reads)
#pragma unroll
      for (int j = 0; j < 4; ++j) {
        if (j == 0)      asm volatile("s_waitcnt lgkmcnt(6)" ::: "memory");
        else if (j == 1) asm volatile("s_waitcnt lgkmcnt(4)" ::: "memory");
        else if (j == 2) asm volatile("s_waitcnt lgkmcnt(2)" ::: "memory");
        else             asm volatile("s_waitcnt lgkmcnt(0)" ::: "memory");
        __builtin_amdgcn_sched_barrier(0);
        union { unsigned long long q[2]; bf16x8 v; } u;
        u.q[0] = tlo[j]; u.q[1] = thi[j];
        const bf16x8 bfv = u.v;
#pragma unroll
        for (int i = 0; i < 4; ++i)
          acc[i][j] = __builtin_amdgcn_mfma_f32_16x16x32_bf16(af[i], bfv, acc[i][j], 0, 0, 0);
      }
    }
  };

  // prologue: tile 0 staged directly; tile 1's B loads issued early (depth-2 pipe)
  stageA(0, 0);
  {
    float4 br0[4];
    loadB(br0, 0);
    writeB(br0, 0);
  }
  float4 brE[4], brO[4];
  loadB(brO, 1);                 // in flight across compute(kt=0)
  __syncthreads();

  // manually 2-unrolled K loop: tile kt lives in buf kt&1; all br indexing static
  for (int kt = 0; kt < 14; kt += 2) {
    // even step: cur buf 0, next buf 1 (tile kt+1, data in brO)
    loadB(brE, kt + 2);
    stageA(kt + 1, 1);
    compute(0);
    writeB(brO, 1);
    __syncthreads();
    // odd step: cur buf 1, next buf 0 (tile kt+2, data in brE)
    loadB(brO, kt + 3);
    stageA(kt + 2, 0);
    compute(1);
    writeB(brE, 0);
    __syncthreads();
  }
  // kt = 14: stage tile 15 only
  stageA(15, 1);
  compute(0);
  writeB(brO, 1);
  __syncthreads();

  // epilogue-data hoist (EPI==2): issue token/weight loads before the last compute
  int   tok[4];
  float wv4[4];
  if (EPI == 2) {
#pragma unroll
    for (int i = 0; i < 4; ++i) {
      const int row  = m0 + wr * 64 + i * 16 + (lane >> 4) * 4;
      // each lane needs rows row..row+3; lane-quad shares; load per-r inside epilogue
      // hoist only the slot-base values used first (r=0); rest load below.
      const int slot = e * CAPN + row;
      tok[i] = expert_tokens[slot];
      wv4[i] = w_ec[slot];
    }
  }

  // kt = 15
  compute(1);

  if (EPI == 1) {
#pragma unroll
    for (int i = 0; i < 4; ++i) {
#pragma unroll
      for (int r = 0; r < 4; ++r) {
        const int row = m0 + wr * 64 + i * 16 + (lane >> 4) * 4 + r;
        u16* hp = Hout + ((size_t)e * 512 + row) * 1024 + n0 + wc * 64 + (lane & 15);
#pragma unroll
        for (int j = 0; j < 4; ++j) hp[j * 16] = f2bf(gelu_tanh(acc[i][j][r]));
      }
    }
  } else {
#pragma unroll
    for (int i = 0; i < 4; ++i) {
#pragma unroll
      for (int r = 0; r < 4; ++r) {
        const int row  = m0 + wr * 64 + i * 16 + (lane >> 4) * 4 + r;
        const int slot = e * CAPN + row;
        const int t = (r == 0) ? tok[i] : expert_tokens[slot];
        if (t >= 0) {
          const float w = (r == 0) ? wv4[i] : w_ec[slot];
          float* op = out + (size_t)t * DIM + n0 + wc * 64 + (lane & 15);
#pragma unroll
          for (int j = 0; j < 4; ++j) atomicAdd(op + j * 16, acc[i][j][r] * w);
        }
      }
    }
  }
}

// ---------- launch ----------
extern "C" void kernel_launch(void* const* d_in, const int* in_sizes, int n_in,
                              void* d_out, int out_size, void* d_ws, size_t ws_size,
                              hipStream_t stream)
{
  const float* h  = (const float*)d_in[0];
  const float* Wr = (const float*)d_in[1];
  const float* W1 = (const float*)d_in[2];
  const float* W2 = (const float*)d_in[3];
  float* out = (float*)d_out;

  char* ws = (char*)d_ws;
  u16* Xg  = (u16*)(ws);                          // 16777216 B
  u16* Hb  = (u16*)(ws + 16777216);               // 16777216 B
  float* logits       = (float*)(ws + 33554432);  // 262144 B
  u32*   topmask      = (u32*)  (ws + 33816576);  // 16384 B
  u32*   keptmask     = (u32*)  (ws + 33832960);  // 16384 B
  int*   expert_tokens= (int*)  (ws + 33849344);  // 32768 B
  float* w_ec         = (float*)(ws + 33882112);  // 32768 B

  // allow >64KB dynamic LDS (gfx950: 160KB/WG); host-side attribute set (r6-proven path)
  (void)hipFuncSetAttribute(reinterpret_cast<const void*>(&gemm_fused_kernel<1>),
                            hipFuncAttributeMaxDynamicSharedMemorySize, LDS_TOTAL);
  (void)hipFuncSetAttribute(reinterpret_cast<const void*>(&gemm_fused_kernel<2>),
                            hipFuncAttributeMaxDynamicSharedMemorySize, LDS_TOTAL);

  router_kernel<<<T_TOK / 4, 256, 0, stream>>>(h, Wr, logits, topmask, keptmask);
  capacity_kernel<<<NE, 1024, 0, stream>>>(logits, topmask, keptmask, expert_tokens);
  prep_kernel<<<T_TOK / 4 + NE * CAPN / 4, 256, 0, stream>>>(
      h, logits, keptmask, expert_tokens, out, Xg, w_ec);
  gemm_fused_kernel<1><<<dim3(8, 2, NE), 512, LDS_TOTAL, stream>>>(Xg, W1, Hb, nullptr, nullptr, nullptr);
  gemm_fused_kernel<2><<<dim3(8, 2, NE), 512, LDS_TOTAL, stream>>>(Hb, W2, nullptr, out, expert_tokens, w_ec);
}